// Round 15
// baseline (145.910 us; speedup 1.0000x reference)
//
#include <hip/hip_runtime.h>
#include <math.h>

#define NTHREADS 256
#define MAXBLOCKS 2048
#define UNROLL 8

// Adaptive Wing loss, fused elementwise + partial reduction.
// THETA=0.5, ALPHA=2.1, W=14, E=1.
//   expo = 2.1 - y
//   p    = 0.5^expo = exp2(-expo)
//   A    = 28*expo*p/(1+p)          [since 0.5^(expo-1) = 2p]
//   loss_large = A*(diff - 0.5) + 14*log1p(p)
//   loss_small = 14*log1p(diff^expo)
// R1->R13: HW transcendentals (v_exp/v_log/v_rcp) took 133us -> 44us.
// R13 counters: VALUBusy 23%, HBM 19%, VGPR 28 -> latency-bound, loads not
// batched. This version: 8-deep explicit load batching (each thread's full
// workload = 8 strided float4-pairs, all 16 dwordx4 loads issued before
// compute) to 4x bytes-in-flight per wave.
// diff==0 edge: v_log(0)=-inf -> exp2(-inf)=0 -> log2(1)=0. Correct limit.

#define W_LN2F 9.70406052783923f   // 14*ln2

__device__ __forceinline__ float awing_elem(float xv, float yv) {
    float expo  = 2.1f - yv;
    float p     = __builtin_amdgcn_exp2f(-expo);
    float l2_1p = __builtin_amdgcn_logf(1.0f + p);      // log2(1+p)
    float A     = 28.0f * expo * p * __builtin_amdgcn_rcpf(1.0f + p);
    float diff  = fabsf(yv - xv);
    // diff^expo = exp2(expo * log2(diff))
    float t     = __builtin_amdgcn_exp2f(expo * __builtin_amdgcn_logf(diff));
    float lsml  = W_LN2F * __builtin_amdgcn_logf(1.0f + t);
    float llrg  = fmaf(A, diff - 0.5f, W_LN2F * l2_1p);
    return (diff < 0.5f) ? lsml : llrg;
}

__global__ __launch_bounds__(NTHREADS) void awing_partial_kernel(
    const float* __restrict__ inp, const float* __restrict__ tgt,
    float* __restrict__ partial, int n)
{
    const int tid    = blockIdx.x * blockDim.x + threadIdx.x;
    const int stride = gridDim.x * blockDim.x;
    const int n4     = n >> 2;

    const float4* __restrict__ in4 = (const float4*)inp;
    const float4* __restrict__ tg4 = (const float4*)tgt;

    float acc = 0.0f;
    int i = tid;

    // Main path: 8 strided float4-pairs per chunk, ALL loads issued before
    // any compute (static indices after unroll -> registers, max MLP).
    for (; i + (UNROLL - 1) * stride < n4; i += UNROLL * stride) {
        float4 x[UNROLL], y[UNROLL];
        #pragma unroll
        for (int u = 0; u < UNROLL; ++u) x[u] = in4[i + u * stride];
        #pragma unroll
        for (int u = 0; u < UNROLL; ++u) y[u] = tg4[i + u * stride];
        #pragma unroll
        for (int u = 0; u < UNROLL; ++u) {
            acc += awing_elem(x[u].x, y[u].x);
            acc += awing_elem(x[u].y, y[u].y);
            acc += awing_elem(x[u].z, y[u].z);
            acc += awing_elem(x[u].w, y[u].w);
        }
    }
    // Strided remainder (n4 not divisible by UNROLL*stride)
    for (; i < n4; i += stride) {
        float4 x = in4[i];
        float4 y = tg4[i];
        acc += awing_elem(x.x, y.x);
        acc += awing_elem(x.y, y.y);
        acc += awing_elem(x.z, y.z);
        acc += awing_elem(x.w, y.w);
    }
    // scalar tail (n % 4 != 0)
    for (int j = (n4 << 2) + tid; j < n; j += stride) {
        acc += awing_elem(inp[j], tgt[j]);
    }

    // wave-64 butterfly reduce
    #pragma unroll
    for (int off = 32; off > 0; off >>= 1)
        acc += __shfl_down(acc, off, 64);

    __shared__ float sacc[NTHREADS / 64];
    const int lane = threadIdx.x & 63;
    const int wid  = threadIdx.x >> 6;
    if (lane == 0) sacc[wid] = acc;
    __syncthreads();
    if (threadIdx.x == 0) {
        float s = 0.0f;
        #pragma unroll
        for (int w = 0; w < NTHREADS / 64; ++w) s += sacc[w];
        partial[blockIdx.x] = s;
    }
}

__global__ __launch_bounds__(NTHREADS) void awing_final_kernel(
    const float* __restrict__ partial, float* __restrict__ out, int nparts)
{
    float acc = 0.0f;
    for (int i = threadIdx.x; i < nparts; i += NTHREADS)
        acc += partial[i];

    #pragma unroll
    for (int off = 32; off > 0; off >>= 1)
        acc += __shfl_down(acc, off, 64);

    __shared__ float sacc[NTHREADS / 64];
    const int lane = threadIdx.x & 63;
    const int wid  = threadIdx.x >> 6;
    if (lane == 0) sacc[wid] = acc;
    __syncthreads();
    if (threadIdx.x == 0) {
        float s = 0.0f;
        #pragma unroll
        for (int w = 0; w < NTHREADS / 64; ++w) s += sacc[w];
        out[0] = s;
    }
}

extern "C" void kernel_launch(void* const* d_in, const int* in_sizes, int n_in,
                              void* d_out, int out_size, void* d_ws, size_t ws_size,
                              hipStream_t stream) {
    const float* inp = (const float*)d_in[0];
    const float* tgt = (const float*)d_in[1];
    float* out       = (float*)d_out;
    float* partial   = (float*)d_ws;   // MAXBLOCKS floats = 8 KB scratch

    const int n = in_sizes[0];

    int nblocks = (n / 4 + NTHREADS - 1) / NTHREADS;
    if (nblocks > MAXBLOCKS) nblocks = MAXBLOCKS;
    if (nblocks < 1) nblocks = 1;

    awing_partial_kernel<<<nblocks, NTHREADS, 0, stream>>>(inp, tgt, partial, n);
    awing_final_kernel<<<1, NTHREADS, 0, stream>>>(partial, out, nblocks);
}

// Round 17
// 145.395 us; speedup vs baseline: 1.0035x; 1.0035x over previous
//
#include <hip/hip_runtime.h>
#include <math.h>

#define NTHREADS 256
#define MAXBLOCKS 2048
#define UNROLL 8

// Adaptive Wing loss, fused elementwise + partial reduction.
// THETA=0.5, ALPHA=2.1, W=14, E=1.
//   expo = 2.1 - y ; p = exp2(-expo) ; A = 28*expo*p/(1+p)
//   loss_large = A*(diff-0.5) + 14*log1p(p) ; loss_small = 14*log1p(diff^expo)
// Ladder: 133us (libm, VALU-bound) -> 44us (HW trans, R13) -> 43us (R15:
// source-level 8-deep batching DEFEATED by backend scheduler, VGPR 24,
// ~2 loads in flight, VALUBusy 23%, stalled 77% on vmcnt).
// R16: pin the schedule with sched_barrier(0) between the 16-load block and
// compute. Every thread runs the main path exactly once (n4 == UNROLL*stride
// for the full-size problem), so the kernel is loads->fence->compute->reduce.
// diff==0 edge: v_log(0)=-inf -> exp2(-inf)=0 -> log2(1)=0. Correct limit.

#define W_LN2F 9.70406052783923f   // 14*ln2

__device__ __forceinline__ float awing_elem(float xv, float yv) {
    float expo  = 2.1f - yv;
    float p     = __builtin_amdgcn_exp2f(-expo);
    float l2_1p = __builtin_amdgcn_logf(1.0f + p);      // log2(1+p)
    float A     = 28.0f * expo * p * __builtin_amdgcn_rcpf(1.0f + p);
    float diff  = fabsf(yv - xv);
    // diff^expo = exp2(expo * log2(diff))
    float t     = __builtin_amdgcn_exp2f(expo * __builtin_amdgcn_logf(diff));
    float lsml  = W_LN2F * __builtin_amdgcn_logf(1.0f + t);
    float llrg  = fmaf(A, diff - 0.5f, W_LN2F * l2_1p);
    return (diff < 0.5f) ? lsml : llrg;
}

__global__ __launch_bounds__(NTHREADS, 4) void awing_partial_kernel(
    const float* __restrict__ inp, const float* __restrict__ tgt,
    float* __restrict__ partial, int n)
{
    const int tid    = blockIdx.x * blockDim.x + threadIdx.x;
    const int stride = gridDim.x * blockDim.x;
    const int n4     = n >> 2;

    const float4* __restrict__ in4 = (const float4*)inp;
    const float4* __restrict__ tg4 = (const float4*)tgt;

    float acc = 0.0f;
    int i = tid;

    // Main path: 8 strided float4-pairs; ALL 16 dwordx4 loads issued first,
    // sched_barrier(0) forbids the scheduler from sinking them to their uses.
    for (; i + (UNROLL - 1) * stride < n4; i += UNROLL * stride) {
        float4 x[UNROLL], y[UNROLL];
        #pragma unroll
        for (int u = 0; u < UNROLL; ++u) x[u] = in4[i + u * stride];
        #pragma unroll
        for (int u = 0; u < UNROLL; ++u) y[u] = tg4[i + u * stride];
        __builtin_amdgcn_sched_barrier(0);   // loads stay above, compute below
        #pragma unroll
        for (int u = 0; u < UNROLL; ++u) {
            acc += awing_elem(x[u].x, y[u].x);
            acc += awing_elem(x[u].y, y[u].y);
            acc += awing_elem(x[u].z, y[u].z);
            acc += awing_elem(x[u].w, y[u].w);
        }
    }
    // Strided remainder (n4 not divisible by UNROLL*stride)
    for (; i < n4; i += stride) {
        float4 x = in4[i];
        float4 y = tg4[i];
        acc += awing_elem(x.x, y.x);
        acc += awing_elem(x.y, y.y);
        acc += awing_elem(x.z, y.z);
        acc += awing_elem(x.w, y.w);
    }
    // scalar tail (n % 4 != 0)
    for (int j = (n4 << 2) + tid; j < n; j += stride) {
        acc += awing_elem(inp[j], tgt[j]);
    }

    // wave-64 butterfly reduce
    #pragma unroll
    for (int off = 32; off > 0; off >>= 1)
        acc += __shfl_down(acc, off, 64);

    __shared__ float sacc[NTHREADS / 64];
    const int lane = threadIdx.x & 63;
    const int wid  = threadIdx.x >> 6;
    if (lane == 0) sacc[wid] = acc;
    __syncthreads();
    if (threadIdx.x == 0) {
        float s = 0.0f;
        #pragma unroll
        for (int w = 0; w < NTHREADS / 64; ++w) s += sacc[w];
        partial[blockIdx.x] = s;
    }
}

__global__ __launch_bounds__(NTHREADS) void awing_final_kernel(
    const float* __restrict__ partial, float* __restrict__ out, int nparts)
{
    float acc = 0.0f;
    for (int i = threadIdx.x; i < nparts; i += NTHREADS)
        acc += partial[i];

    #pragma unroll
    for (int off = 32; off > 0; off >>= 1)
        acc += __shfl_down(acc, off, 64);

    __shared__ float sacc[NTHREADS / 64];
    const int lane = threadIdx.x & 63;
    const int wid  = threadIdx.x >> 6;
    if (lane == 0) sacc[wid] = acc;
    __syncthreads();
    if (threadIdx.x == 0) {
        float s = 0.0f;
        #pragma unroll
        for (int w = 0; w < NTHREADS / 64; ++w) s += sacc[w];
        out[0] = s;
    }
}

extern "C" void kernel_launch(void* const* d_in, const int* in_sizes, int n_in,
                              void* d_out, int out_size, void* d_ws, size_t ws_size,
                              hipStream_t stream) {
    const float* inp = (const float*)d_in[0];
    const float* tgt = (const float*)d_in[1];
    float* out       = (float*)d_out;
    float* partial   = (float*)d_ws;   // MAXBLOCKS floats = 8 KB scratch

    const int n = in_sizes[0];

    int nblocks = (n / 4 + NTHREADS - 1) / NTHREADS;
    if (nblocks > MAXBLOCKS) nblocks = MAXBLOCKS;
    if (nblocks < 1) nblocks = 1;

    awing_partial_kernel<<<nblocks, NTHREADS, 0, stream>>>(inp, tgt, partial, n);
    awing_final_kernel<<<1, NTHREADS, 0, stream>>>(partial, out, nblocks);
}